// Round 1
// baseline (106.964 us; speedup 1.0000x reference)
//
#include <hip/hip_runtime.h>

#define NQ 6
#define DIM 64
#define NL 8

#define KP   136  // Bs row pitch (bf16 elems); 272 B rows: 16B-aligned b128 reads
#define ROWS 128  // samples per block (grid = batch / ROWS = 2048 blocks)

typedef __attribute__((ext_vector_type(8))) short    short8v;   // 8 bf16 = 4 VGPRs
typedef __attribute__((ext_vector_type(4))) float    floatx4;
typedef __attribute__((ext_vector_type(4))) _Float16 half4v;    // 4 f16 = 2 VGPRs

__device__ inline short f2bf_rne(float f) {
    unsigned u = __float_as_uint(f);
    u += 0x7FFF + ((u >> 16) & 1);           // round-to-nearest-even
    return (short)(u >> 16);
}

// ---------------------------------------------------------------------------
// Prep (circuit verified rounds 1-4): build unitary U, emit to ws:
//   Bs[128][KP] bf16 : rows n<64 = Wr[n][*], n>=64 = Wi[n-64][*];
//                      cols k<64 = bf16_hi(W[n][k]), 64<=k<128 = bf16_lo(W[n][k])
//   M5h table (f16) at byte offset 128*KP*2: A-fragment-ready for
//   mfma_f32_16x16x16_f16: entry [c2][lane][j] = M5[c2*16+(lane>>4)*4+j][lane&15]
//   where M5[i][c<4] = sum_q sign(i,q) fc_w[c][q], M5[i][4] = 1, else 0.
// ---------------------------------------------------------------------------
__global__ __launch_bounds__(64) void qnn_prep(
    const float* __restrict__ wts,   // [8*6*3] (phi, theta, omega)
    const float* __restrict__ fc_w,  // [4*6]
    void* __restrict__ ws)
{
    __shared__ float gc[48][4];
    const int n   = threadIdx.x;     // amplitude row 0..63
    const int col = blockIdx.x;      // basis column 0..63

    if (n < 48) {
        float phi = wts[n*3+0], th = wts[n*3+1], om = wts[n*3+2];
        float ch = cosf(0.5f*th), sh = sinf(0.5f*th);
        float p  = 0.5f*(phi+om), m  = 0.5f*(phi-om);
        gc[n][0] = cosf(p)*ch;
        gc[n][1] = sinf(p)*ch;
        gc[n][2] = cosf(m)*sh;
        gc[n][3] = sinf(m)*sh;
    }
    __syncthreads();

    float ar = (n == col) ? 1.0f : 0.0f;
    float ai = 0.0f;

    #pragma unroll
    for (int l = 0; l < NL; ++l) {
        #pragma unroll
        for (int q = 0; q < NQ; ++q) {
            const int g     = l*NQ + q;
            const int shift = 5 - q;
            const int mask  = 1 << shift;
            const int b     = (n >> shift) & 1;
            const float cpch = gc[g][0];
            const float spch = gc[g][1];
            const float cmsh = gc[g][2];
            const float smsh = gc[g][3];
            const float pr = __shfl_xor(ar, mask, 64);
            const float pi = __shfl_xor(ai, mask, 64);
            const float udr = cpch;
            const float udi = b ?  spch : -spch;
            const float uor = b ?  cmsh : -cmsh;
            const float uoi = -smsh;
            const float nr = udr*ar - udi*ai + uor*pr - uoi*pi;
            const float ni = udr*ai + udi*ar + uor*pi + uoi*pr;
            ar = nr; ai = ni;
        }
        const int r = (l % (NQ - 1)) + 1;
        #pragma unroll
        for (int q = 0; q < NQ; ++q) {
            const int t     = (q + r) % NQ;
            const int cmask = 1 << (5 - q);
            const int tmask = 1 << (5 - t);
            const float pr = __shfl_xor(ar, tmask, 64);
            const float pi = __shfl_xor(ai, tmask, 64);
            const bool ctrl = (n & cmask) != 0;
            ar = ctrl ? pr : ar;
            ai = ctrl ? pi : ai;
        }
    }

    unsigned short* Bs = (unsigned short*)ws;
    unsigned short hr = (unsigned short)f2bf_rne(ar);
    float hrf = __uint_as_float((unsigned)hr << 16);
    unsigned short lr = (unsigned short)f2bf_rne(ar - hrf);
    unsigned short hi = (unsigned short)f2bf_rne(ai);
    float hif = __uint_as_float((unsigned)hi << 16);
    unsigned short li = (unsigned short)f2bf_rne(ai - hif);
    Bs[n*KP + col]           = hr;
    Bs[n*KP + 64 + col]      = lr;
    Bs[(64+n)*KP + col]      = hi;
    Bs[(64+n)*KP + 64 + col] = li;

    if (col == 0) {
        const int cp = n & 15;            // c' = l15
        const int qd = n >> 4;            // quad
        half4v* Mo = (half4v*)((char*)ws + 128*KP*2);
        #pragma unroll
        for (int c2 = 0; c2 < 4; ++c2) {
            half4v h4;
            #pragma unroll
            for (int j = 0; j < 4; ++j) {
                const int i = c2*16 + qd*4 + j;
                float v = 0.f;
                if (cp < 4) {
                    #pragma unroll
                    for (int q = 0; q < NQ; ++q) {
                        const float sgn = 1.0f - 2.0f*(float)((i >> (5-q)) & 1);
                        v = fmaf(sgn, fc_w[cp*NQ + q], v);
                    }
                } else if (cp == 4) {
                    v = 1.0f;             // ones column -> ss
                }
                h4[j] = (_Float16)v;
            }
            Mo[c2*64 + n] = h4;
        }
    }
}

// ---------------------------------------------------------------------------
// Main, v2: occupancy restructure. 2048 blocks x 256 thr, one 128-sample tile
// per block. W staged via global_load_lds (async, no VGPR round-trip); x
// single-buffered in registers (issued before staging so both latencies
// overlap); a2/fc_b loads hoisted past the K-loop to shrink its live set.
// Target: ~140 VGPR -> 3+ waves/SIMD (vs 2 before); cross-block TLP replaces
// the old intra-wave tile prefetch.
// ---------------------------------------------------------------------------
__global__ __launch_bounds__(256, 3) void qnn_main(
    const float* __restrict__ x,
    const float* __restrict__ fc_b,
    const void* __restrict__ wsv,
    float* __restrict__ out)
{
    __shared__ __align__(16) unsigned short Bs[128*KP];   // 34816 B

    const int tid  = threadIdx.x;
    const int lane = tid & 63;
    const int w    = tid >> 6;
    const int l15  = lane & 15;
    const int quad = lane >> 4;
    const int rbase = w*32 + l15;               // lane's row offset in the tile

    // --- issue x loads first (independent of staging) ---
    float4 xr[2][2][2];                         // [st][h][pair] = 32 VGPR
    {
        const float* xt = x + ((size_t)blockIdx.x*ROWS + rbase)*DIM + quad*8;
        #pragma unroll
        for (int st = 0; st < 2; ++st)
            #pragma unroll
            for (int h = 0; h < 2; ++h) {
                xr[st][h][0] = *(const float4*)(xt + st*16*DIM + h*32);
                xr[st][h][1] = *(const float4*)(xt + st*16*DIM + h*32 + 4);
            }
    }

    // --- async stage W (bf16 hi|lo) straight into LDS ---
    {
        const char* bg = (const char*)wsv;
        #pragma unroll
        for (int i = 0; i < 9; ++i) {
            const int idx = i*256 + tid;        // 16 B chunks; 2176 total (34*64)
            if (idx < 128*KP*2/16) {
                __builtin_amdgcn_global_load_lds(
                    (const __attribute__((address_space(1))) unsigned*)(bg + (size_t)idx*16),
                    (__attribute__((address_space(3))) unsigned*)((char*)Bs + (i*256 + w*64)*16),
                    16, 0, 0);
            }
        }
    }

    __syncthreads();   // x regs + Bs both drained here; only barrier

    // --- convert x tile to bf16 B-fragments (frees xr) ---
    short8v xf[2][2];
    #pragma unroll
    for (int st = 0; st < 2; ++st)
        #pragma unroll
        for (int h = 0; h < 2; ++h) {
            const float4 u0 = xr[st][h][0];
            const float4 u1 = xr[st][h][1];
            short8v a;
            a[0]=f2bf_rne(u0.x); a[1]=f2bf_rne(u0.y);
            a[2]=f2bf_rne(u0.z); a[3]=f2bf_rne(u0.w);
            a[4]=f2bf_rne(u1.x); a[5]=f2bf_rne(u1.y);
            a[6]=f2bf_rne(u1.z); a[7]=f2bf_rne(u1.w);
            xf[st][h] = a;
        }

    // --- K-loop: A = W (LDS), B = x (registers) ---
    floatx4 acc[2][8];
    #pragma unroll
    for (int st = 0; st < 2; ++st)
        #pragma unroll
        for (int mt = 0; mt < 8; ++mt)
            acc[st][mt] = (floatx4){0.f, 0.f, 0.f, 0.f};

    #pragma unroll
    for (int kk = 0; kk < 4; ++kk) {
        const int h  = kk & 1;                  // x-hi reused for W-lo K range
        const int bk = (kk << 5) + quad*8;
        #pragma unroll
        for (int mt = 0; mt < 8; ++mt) {
            const short8v wf = *(const short8v*)&Bs[(mt*16 + l15)*KP + bk];
            acc[0][mt] = __builtin_amdgcn_mfma_f32_16x16x32_bf16(wf, xf[0][h], acc[0][mt], 0, 0, 0);
            acc[1][mt] = __builtin_amdgcn_mfma_f32_16x16x32_bf16(wf, xf[1][h], acc[1][mt], 0, 0, 0);
        }
    }

    // --- M5 A-fragments + bias (loaded late: epilogue-only live range) ---
    const half4v* Mg = (const half4v*)((const char*)wsv + 128*KP*2);
    half4v a2[4];
    #pragma unroll
    for (int c2 = 0; c2 < 4; ++c2) a2[c2] = Mg[c2*64 + lane];
    const float b0 = fc_b[0], b1 = fc_b[1], b2 = fc_b[2], b3 = fc_b[3];

    // --- epilogue: out[c][s] = sum_i M5[i][c] * p[i][s] via f16 MFMA ---
    const size_t s0 = (size_t)blockIdx.x * ROWS;
    #pragma unroll
    for (int st = 0; st < 2; ++st) {
        floatx4 d2 = (floatx4){0.f, 0.f, 0.f, 0.f};
        #pragma unroll
        for (int c2 = 0; c2 < 4; ++c2) {
            half4v pb;
            #pragma unroll
            for (int r = 0; r < 4; ++r) {
                const float re = acc[st][c2][r];
                const float im = acc[st][c2 + 4][r];
                pb[r] = (_Float16)fmaf(re, re, im*im);
            }
            d2 = __builtin_amdgcn_mfma_f32_16x16x16f16(a2[c2], pb, d2, 0, 0, 0);
        }
        // d2 reg r = D2[row=quad*4+r][col=l15]; rows 0..3 = logits, row 4 = ss
        const float ssv = __shfl_xor(d2[0], 16, 64);  // quad0 <- quad1 row4
        if (quad == 0) {
            const float inv = 1.0f / ssv;
            float4 o;
            o.x = fmaf(d2[0], inv, b0);
            o.y = fmaf(d2[1], inv, b1);
            o.z = fmaf(d2[2], inv, b2);
            o.w = fmaf(d2[3], inv, b3);
            *(float4*)(out + (s0 + w*32 + st*16 + l15)*4) = o;
        }
    }
}

extern "C" void kernel_launch(void* const* d_in, const int* in_sizes, int n_in,
                              void* d_out, int out_size, void* d_ws, size_t ws_size,
                              hipStream_t stream) {
    const float* x    = (const float*)d_in[0];   // [262144, 64]
    const float* wts  = (const float*)d_in[1];   // [8, 6, 3]
    const float* fc_w = (const float*)d_in[2];   // [4, 6]
    const float* fc_b = (const float*)d_in[3];   // [4]
    float* out = (float*)d_out;                  // [262144, 4]

    const int batch = in_sizes[0] / DIM;         // 262144

    qnn_prep<<<DIM, DIM, 0, stream>>>(wts, fc_w, d_ws);
    qnn_main<<<batch / ROWS, 256, 0, stream>>>(x, fc_b, d_ws, out);
}